// Round 10
// baseline (176.532 us; speedup 1.0000x reference)
//
#include <hip/hip_runtime.h>

#define Hn 28
#define PQ 784     // 28*28
#define NI 128     // B*I
#define DONE_MAGIC 0x5A5A5A5A

typedef __attribute__((ext_vector_type(8))) short short8v;   // 8 bf16 (4 VGPRs)
typedef __attribute__((ext_vector_type(4))) short short4v;   // 4 bf16 (b64)
typedef __attribute__((ext_vector_type(4))) float float4v;   // MFMA C/D

__device__ __forceinline__ short f2bf(float x) {
    union { float f; unsigned u; } a; a.f = x;
    unsigned r = a.u + 0x7FFF + ((a.u >> 16) & 1);   // RNE
    return (short)(r >> 16);
}

// Single launch, 784 blocks x 256, all co-resident (4 blocks/CU x 256 CU = 1024 slots).
// Blocks 0..127: produce vTb (bf16 transpose) + Vsum into ws, publish flag[b].
// All blocks: spin on flags (agent scope), then run the R6 fused body for rs=blockIdx.
// LDS = 10240+5120+16512+4096+512 = 36480 B -> 4 blocks/CU.
__global__ __launch_bounds__(256, 4) void fused_kernel(
    const float* __restrict__ v, const float* __restrict__ W1,
    const float* __restrict__ b1, const float* __restrict__ W2,
    const float* __restrict__ b2, const float* __restrict__ bias,
    float* __restrict__ out, short* __restrict__ vTb,
    float* __restrict__ Vsum, int* __restrict__ flags)
{
    __shared__ __align__(16) char smem[36480];
    short* sV   = (short*)smem;            // [ni][p] pad40 bf16  10240 B
    short* sHt  = (short*)(smem + 10240);  // [c][p]  pad40 bf16   5120 B
    short* sTa  = (short*)(smem + 15360);  // [n8][k=c*16+i] bf16 16512 B
    float* sRed = (float*)(smem + 31872);  // wave partials        4096 B
    float* sVs  = (float*)(smem + 35968);  //                       512 B

    const int t = threadIdx.x;
    const int b = blockIdx.x;

    // wave/lane ids
    const int w  = t >> 6;
    const int l  = t & 63;
    const int lm = l & 15;
    const int q  = l >> 4;
    const int k0 = q * 8;

    // ---- W2 fragment preload (R9-style): coalesced fp32, cvt once, 32 VGPRs.
    short8v wcache[8];
    #pragma unroll
    for (int st = 0; st < 8; ++st) {
        const int kb = w * 256 + st * 32 + k0;
        const int c  = kb >> 4;
        const int i0 = kb & 15;                                 // 0 or 8
        const float* wrow = &W2[c * 256 + lm * 16 + i0];
        const float4 wf0 = *(const float4*)&wrow[0];
        const float4 wf1 = *(const float4*)&wrow[4];
        short8v bfr;
        bfr[0] = f2bf(wf0.x); bfr[1] = f2bf(wf0.y);
        bfr[2] = f2bf(wf0.z); bfr[3] = f2bf(wf0.w);
        bfr[4] = f2bf(wf1.x); bfr[5] = f2bf(wf1.y);
        bfr[6] = f2bf(wf1.z); bfr[7] = f2bf(wf1.w);
        wcache[st] = bfr;
    }

    // ================= producers: blocks 0..127 transpose v tile ni=b =================
    if (b < NI) {
        float* sT = (float*)smem;          // [s][p] pad29, 3248 B (overlaps sV)
        const int ni = b;
        #pragma unroll
        for (int k = 0; k < 4; ++k) {      // coalesced read of the 28x28 tile
            const int e = t + 256 * k;
            if (e < PQ) {
                const int p = e / Hn;
                const int s = e - p * Hn;
                sT[s * 29 + p] = v[ni * PQ + e];
            }
        }
        __syncthreads();
        #pragma unroll
        for (int k = 0; k < 2; ++k) {      // 16 lanes x short2 = one 64B line
            const int idx = t + 256 * k;
            if (idx < Hn * 16) {
                const int s = idx >> 4;
                const int e2 = idx & 15;
                const int p0 = 2 * e2;
                short2 h;
                h.x = (p0     < Hn) ? f2bf(sT[s * 29 + p0])     : (short)0;
                h.y = (p0 + 1 < Hn) ? f2bf(sT[s * 29 + p0 + 1]) : (short)0;
                *(short2*)(vTb + s * (NI * 32) + ni * 32 + p0) = h;
            }
        }
        if (t < Hn) {                      // fp32 column sums from LDS
            const int s = t;
            float acc = 0.0f;
            #pragma unroll
            for (int p = 0; p < Hn; ++p) acc += sT[s * 29 + p];
            Vsum[s * NI + ni] = acc;
        }
        __threadfence();                   // agent-scope ordering of the stores above
        __syncthreads();                   // all producer stores drained (vmcnt(0))
        if (t == 0)
            __hip_atomic_store(&flags[b], DONE_MAGIC, __ATOMIC_RELEASE,
                               __HIP_MEMORY_SCOPE_AGENT);
        __syncthreads();                   // re-converge before F reuses smem
    }

    // ================= spin: wait for all 128 producer flags =================
    {
        const int slot = t & 127;          // 256 threads cover 128 slots 2x
        while (__hip_atomic_load(&flags[slot], __ATOMIC_ACQUIRE,
                                 __HIP_MEMORY_SCOPE_AGENT) != DONE_MAGIC) {
            __builtin_amdgcn_s_sleep(8);
        }
    }
    __syncthreads();

    // ================= phase F: R6 fused body, rs = blockIdx =================
    const int rs = b;
    const int r = rs / Hn;
    const int s = rs - r * Hn;

    // ---- stage V slice: ws [s][ni][p(32)] (contiguous 8KB) -> sV rows stride 40
    {
        const short* src = vTb + s * (NI * 32);
        #pragma unroll
        for (int j = 0; j < 2; ++j) {
            const int idx = t + 256 * j;       // 0..511
            const int ni = idx >> 2;
            const int ko = (idx & 3) * 8;
            *(short8v*)&sV[ni * 40 + ko] = *(const short8v*)(src + ni * 32 + ko);
        }
    }
    if (t < NI) sVs[t] = Vsum[s * NI + t];

    // ---- phase B: sHt[c][p] = bf16( Σ_q gelu ) via Euler–Maclaurin
    {
        const int c = t & 63;
        const int pg = t >> 6;               // 4 groups x 7 p
        const float w0 = W1[c];
        const float Wc = W1[64 + c];
        const float w2 = W1[128 + c];
        const float w3 = W1[192 + c];
        const float inv = 1.0f / 28.0f;
        const float base = ((r + 0.5f) * inv) * w2 + ((s + 0.5f) * inv) * w3
                         + b1[c] + 0.5f * Wc;
        const float w0i = inv * w0;
        const float W2c = Wc * Wc;
        const float c2 = 1.1651786f * W2c;            // 1827/(2*784)
        const float c4 = 0.0145213f * (W2c * W2c);    // 214215.75/(614656*24)
        #pragma unroll
        for (int pi = 0; pi < 7; ++pi) {
            const int p = pg * 7 + pi;
            const float m  = fmaf((float)p + 0.5f, w0i, base);
            const float m2 = m * m;
            const float E  = __builtin_amdgcn_exp2f(m2 * -0.72134752f);  // e^{-m²/2}
            const float az = fabsf(m) * 0.70710678f;
            const float tt = __builtin_amdgcn_rcpf(fmaf(0.3275911f, az, 1.0f));
            float poly = fmaf(tt, 1.061405429f, -1.453152027f);
            poly = fmaf(tt, poly, 1.421413741f);
            poly = fmaf(tt, poly, -0.284496736f);
            poly = fmaf(tt, poly, 0.254829592f);
            poly = poly * tt;
            float erfv = fmaf(-poly, E, 1.0f);
            erfv = (m < 0.0f) ? -erfv : erfv;
            const float g   = 0.5f * m * (1.0f + erfv);
            const float phi = 0.39894228f * E;
            const float p4  = fmaf(-m2, m2, fmaf(7.0f, m2, -4.0f));  // −m⁴+7m²−4
            const float corr = phi * fmaf(c4, p4, c2 * (2.0f - m2));
            sHt[c * 40 + p] = f2bf(fmaf(28.0f, g, corr));
        }
        if (pg == 3) *(uint2*)&sHt[c * 40 + 28] = make_uint2(0u, 0u);
    }
    __syncthreads();

    // ---- phase D (MFMA): T[ni][c] = sum_p V[ni][p] * H[p][c]
    {
        short8v aF[2], bF[4];
        aF[0] = *(const short8v*)&sV[(32 * w + lm) * 40 + k0];
        aF[1] = *(const short8v*)&sV[(32 * w + 16 + lm) * 40 + k0];
        #pragma unroll
        for (int nt = 0; nt < 4; ++nt)
            bF[nt] = *(const short8v*)&sHt[(16 * nt + lm) * 40 + k0];

        float4v accD[2][4];
        #pragma unroll
        for (int mt = 0; mt < 2; ++mt)
            #pragma unroll
            for (int nt = 0; nt < 4; ++nt)
                accD[mt][nt] = __builtin_amdgcn_mfma_f32_16x16x32_bf16(
                    aF[mt], bF[nt], (float4v)(0.0f), 0, 0, 0);

        // pack T to sTa[n8][c*16+i]: ni = 32w+16mt+4q+reg -> n8=2w+mt, i=4q+reg
        #pragma unroll
        for (int mt = 0; mt < 2; ++mt) {
            const int n8 = 2 * w + mt;
            #pragma unroll
            for (int nt = 0; nt < 4; ++nt) {
                const int c = 16 * nt + lm;
                short4v pk;
                pk[0] = f2bf(accD[mt][nt][0]);
                pk[1] = f2bf(accD[mt][nt][1]);
                pk[2] = f2bf(accD[mt][nt][2]);
                pk[3] = f2bf(accD[mt][nt][3]);
                *(short4v*)&sTa[n8 * 1032 + c * 16 + 4 * q] = pk;
            }
        }
    }
    __syncthreads();

    // ---- phase D2 (MFMA): out[n8][o] = sum_k Ta[n8][k] * W2[k][o], W2 from regs
    float4v accO = (float4v)(0.0f);
    #pragma unroll
    for (int st = 0; st < 8; ++st) {
        const int kb = w * 256 + st * 32 + k0;
        const short8v a = *(const short8v*)&sTa[(lm & 7) * 1032 + kb];
        accO = __builtin_amdgcn_mfma_f32_16x16x32_bf16(a, wcache[st], accO, 0, 0, 0);
    }
    #pragma unroll
    for (int reg = 0; reg < 4; ++reg) {
        const int m = q * 4 + reg;                 // 0..15, valid m<8
        sRed[w * 256 + m * 16 + lm] = accO[reg];
    }
    __syncthreads();

    // ---- E: reduce 4 wave-partials, add b2 term + bias, store
    if (t < NI) {
        const int n8 = t >> 4;
        const int o  = t & 15;
        const int e  = n8 * 16 + o;
        const float tot = sRed[e] + sRed[256 + e] + sRed[512 + e] + sRed[768 + e];
        float bsum = 0.0f;
        #pragma unroll
        for (int i = 0; i < 16; ++i)
            bsum = fmaf(b2[o * 16 + i], sVs[n8 * 16 + i], bsum);
        out[(n8 * 16 + o) * PQ + rs] = (tot + 28.0f * bsum) * (1.0f / 784.0f) + bias[o];
    }
}

extern "C" void kernel_launch(void* const* d_in, const int* in_sizes, int n_in,
                              void* d_out, int out_size, void* d_ws, size_t ws_size,
                              hipStream_t stream) {
    const float* v    = (const float*)d_in[0];  // (8,16,28,28)
    const float* W1   = (const float*)d_in[1];  // (4,64)
    const float* b1   = (const float*)d_in[2];  // (64,)
    const float* W2   = (const float*)d_in[3];  // (64,256)
    const float* b2   = (const float*)d_in[4];  // (256,)
    const float* bias = (const float*)d_in[5];  // (16,1,1)
    float* out = (float*)d_out;                 // (8,16,28,28) fp32

    char* ws = (char*)d_ws;
    short* vTb  = (short*)(ws);                 // 28*128*32*2 = 229376 B
    float* Vsum = (float*)(ws + 229376);        // 28*128*4    =  14336 B
    int*   flags = (int*)(ws + 243712);         // 128*4; poison 0xAA.. != DONE_MAGIC

    fused_kernel<<<PQ, 256, 0, stream>>>(v, W1, b1, W2, b2, bias, out,
                                         vTb, Vsum, flags);
}

// Round 11
// 72.747 us; speedup vs baseline: 2.4266x; 2.4266x over previous
//
#include <hip/hip_runtime.h>

#define Hn 28
#define PQ 784     // 28*28
#define NI 128     // B*I

typedef __attribute__((ext_vector_type(8))) short short8v;   // 8 bf16 (4 VGPRs)
typedef __attribute__((ext_vector_type(4))) short short4v;   // 4 bf16 (b64)
typedef __attribute__((ext_vector_type(4))) float float4v;   // MFMA C/D

__device__ __forceinline__ short f2bf(float x) {
    union { float f; unsigned u; } a; a.f = x;
    unsigned r = a.u + 0x7FFF + ((a.u >> 16) & 1);   // RNE
    return (short)(r >> 16);
}

// blocks 0..127 (ni-major): LDS-tiled transpose (R6, measured best).
// block 128: W2b = bf16(W2).
__global__ __launch_bounds__(256) void prep_kernel(
    const float* __restrict__ v, const float* __restrict__ W2,
    short* __restrict__ vTb, short* __restrict__ W2b, float* __restrict__ Vsum)
{
    const int b = blockIdx.x;
    const int t = threadIdx.x;
    if (b == NI) {   // W2 fp32 -> bf16, coalesced
        for (int e = t; e < 8192; e += 256) {
            const float2 f = ((const float2*)W2)[e];
            short2 h; h.x = f2bf(f.x); h.y = f2bf(f.y);
            ((short2*)W2b)[e] = h;
        }
        return;
    }
    __shared__ float sT[Hn * 29];        // [s][p] pad29, 3248 B
    const int ni = b;
    #pragma unroll
    for (int k = 0; k < 4; ++k) {        // coalesced read of the 28x28 tile
        const int e = t + 256 * k;
        if (e < PQ) {
            const int p = e / Hn;
            const int s = e - p * Hn;
            sT[s * 29 + p] = v[ni * PQ + e];
        }
    }
    __syncthreads();
    #pragma unroll
    for (int k = 0; k < 2; ++k) {        // 16 lanes x short2 = one 64B line
        const int idx = t + 256 * k;
        if (idx < Hn * 16) {
            const int s = idx >> 4;
            const int e2 = idx & 15;
            const int p0 = 2 * e2;
            short2 h;
            h.x = (p0     < Hn) ? f2bf(sT[s * 29 + p0])     : (short)0;
            h.y = (p0 + 1 < Hn) ? f2bf(sT[s * 29 + p0 + 1]) : (short)0;
            *(short2*)(vTb + s * (NI * 32) + ni * 32 + p0) = h;
        }
    }
    if (t < Hn) {                        // fp32 column sums from LDS
        const int s = t;
        float acc = 0.0f;
        #pragma unroll
        for (int p = 0; p < Hn; ++p) acc += sT[s * 29 + p];
        Vsum[s * NI + ni] = acc;
    }
}

// One block per (r,s). LDS overlay: sTa reuses sV+sHt space (dead after the
// phase-D fragment reads). LDS = max(15360,16512)+4096+512 = 21120 B
// -> 7 blocks/CU -> all 784 blocks co-resident in ONE round.
__global__ __launch_bounds__(256, 7) void fused_kernel(
    const short* __restrict__ vTb, const short* __restrict__ W2b,
    const float* __restrict__ Vsum,
    const float* __restrict__ W1, const float* __restrict__ b1,
    const float* __restrict__ b2, const float* __restrict__ bias,
    float* __restrict__ out)
{
    __shared__ __align__(16) char smem[21120];
    short* sV   = (short*)smem;            // [ni][p] pad40 bf16  10240 B ┐ dead after
    short* sHt  = (short*)(smem + 10240);  // [c][p]  pad40 bf16   5120 B ┘ D-frag reads
    short* sTa  = (short*)smem;            // [n8][k] bf16 16512 B (OVERLAY)
    float* sRed = (float*)(smem + 16512);  // psum halves / wave partials 4096 B
    float* sVs  = (float*)(smem + 20608);  //                       512 B

    const int t = threadIdx.x;
    const int rs = blockIdx.x;
    const int r = rs / Hn;
    const int s = rs - r * Hn;

    // ---- stage V slice: ws [s][ni][p(32)] (contiguous 8KB) -> sV rows stride 40
    {
        const short* src = vTb + s * (NI * 32);
        #pragma unroll
        for (int j = 0; j < 2; ++j) {
            const int idx = t + 256 * j;       // 0..511
            const int ni = idx >> 2;
            const int ko = (idx & 3) * 8;
            *(short8v*)&sV[ni * 40 + ko] = *(const short8v*)(src + ni * 32 + ko);
        }
    }
    if (t < NI) sVs[t] = Vsum[s * NI + t];

    // ---- phase B: sHt[c][p] = bf16( Σ_q gelu ) via Euler–Maclaurin
    {
        const int c = t & 63;
        const int pg = t >> 6;               // 4 groups x 7 p
        const float w0 = W1[c];
        const float Wc = W1[64 + c];
        const float w2 = W1[128 + c];
        const float w3 = W1[192 + c];
        const float inv = 1.0f / 28.0f;
        const float base = ((r + 0.5f) * inv) * w2 + ((s + 0.5f) * inv) * w3
                         + b1[c] + 0.5f * Wc;
        const float w0i = inv * w0;
        const float W2c = Wc * Wc;
        const float c2 = 1.1651786f * W2c;            // 1827/(2*784)
        const float c4 = 0.0145213f * (W2c * W2c);    // 214215.75/(614656*24)
        #pragma unroll
        for (int pi = 0; pi < 7; ++pi) {
            const int p = pg * 7 + pi;
            const float m  = fmaf((float)p + 0.5f, w0i, base);
            const float m2 = m * m;
            const float E  = __builtin_amdgcn_exp2f(m2 * -0.72134752f);  // e^{-m²/2}
            const float az = fabsf(m) * 0.70710678f;
            const float tt = __builtin_amdgcn_rcpf(fmaf(0.3275911f, az, 1.0f));
            float poly = fmaf(tt, 1.061405429f, -1.453152027f);
            poly = fmaf(tt, poly, 1.421413741f);
            poly = fmaf(tt, poly, -0.284496736f);
            poly = fmaf(tt, poly, 0.254829592f);
            poly = poly * tt;
            float erfv = fmaf(-poly, E, 1.0f);
            erfv = (m < 0.0f) ? -erfv : erfv;
            const float g   = 0.5f * m * (1.0f + erfv);
            const float phi = 0.39894228f * E;
            const float p4  = fmaf(-m2, m2, fmaf(7.0f, m2, -4.0f));  // −m⁴+7m²−4
            const float corr = phi * fmaf(c4, p4, c2 * (2.0f - m2));
            sHt[c * 40 + p] = f2bf(fmaf(28.0f, g, corr));
        }
        if (pg == 3) *(uint2*)&sHt[c * 40 + 28] = make_uint2(0u, 0u);
    }
    __syncthreads();                         // bar1: sV, sHt ready

    // ---- phase D (MFMA): T[ni][c] = sum_p V[ni][p] * H[p][c]
    const int w  = t >> 6;          // wave 0..3
    const int l  = t & 63;
    const int lm = l & 15;
    const int q  = l >> 4;
    const int k0 = q * 8;

    short8v aF[2], bF[4];
    aF[0] = *(const short8v*)&sV[(32 * w + lm) * 40 + k0];
    aF[1] = *(const short8v*)&sV[(32 * w + 16 + lm) * 40 + k0];
    #pragma unroll
    for (int nt = 0; nt < 4; ++nt)
        bF[nt] = *(const short8v*)&sHt[(16 * nt + lm) * 40 + k0];

    float4v accD[2][4];
    #pragma unroll
    for (int mt = 0; mt < 2; ++mt)
        #pragma unroll
        for (int nt = 0; nt < 4; ++nt)
            accD[mt][nt] = __builtin_amdgcn_mfma_f32_16x16x32_bf16(
                aF[mt], bF[nt], (float4v)(0.0f), 0, 0, 0);

    __syncthreads();                         // bar2: all sV/sHt reads done; sTa may overlay

    // pack T to sTa[n8][c*16+i]: ni = 32w+16mt+4q+reg -> n8=2w+mt, i=4q+reg
    #pragma unroll
    for (int mt = 0; mt < 2; ++mt) {
        const int n8 = 2 * w + mt;
        #pragma unroll
        for (int nt = 0; nt < 4; ++nt) {
            const int c = 16 * nt + lm;
            short4v pk;
            pk[0] = f2bf(accD[mt][nt][0]);
            pk[1] = f2bf(accD[mt][nt][1]);
            pk[2] = f2bf(accD[mt][nt][2]);
            pk[3] = f2bf(accD[mt][nt][3]);
            *(short4v*)&sTa[n8 * 1032 + c * 16 + 4 * q] = pk;
        }
    }
    __syncthreads();                         // bar3: sTa ready

    // ---- phase D2 (MFMA): out[n8][o] = sum_k Ta[n8][k] * W2b[k][o]
    float4v accO = (float4v)(0.0f);
    #pragma unroll
    for (int st = 0; st < 8; ++st) {
        const int kb = w * 256 + st * 32 + k0;
        const short8v a = *(const short8v*)&sTa[(lm & 7) * 1032 + kb];
        const int c  = kb >> 4;
        const int i0 = kb & 15;                                        // 0 or 8
        const short8v bfr = *(const short8v*)&W2b[c * 256 + lm * 16 + i0];
        accO = __builtin_amdgcn_mfma_f32_16x16x32_bf16(a, bfr, accO, 0, 0, 0);
    }
    #pragma unroll
    for (int reg = 0; reg < 4; ++reg) {
        const int m = q * 4 + reg;                 // 0..15, valid m<8
        sRed[w * 256 + m * 16 + lm] = accO[reg];
    }
    __syncthreads();                         // bar4: sRed ready

    // ---- E: reduce 4 wave-partials, add b2 term + bias, store
    if (t < NI) {
        const int n8 = t >> 4;
        const int o  = t & 15;
        const int e  = n8 * 16 + o;
        const float tot = sRed[e] + sRed[256 + e] + sRed[512 + e] + sRed[768 + e];
        float bsum = 0.0f;
        #pragma unroll
        for (int i = 0; i < 16; ++i)
            bsum = fmaf(b2[o * 16 + i], sVs[n8 * 16 + i], bsum);
        out[(n8 * 16 + o) * PQ + rs] = (tot + 28.0f * bsum) * (1.0f / 784.0f) + bias[o];
    }
}

extern "C" void kernel_launch(void* const* d_in, const int* in_sizes, int n_in,
                              void* d_out, int out_size, void* d_ws, size_t ws_size,
                              hipStream_t stream) {
    const float* v    = (const float*)d_in[0];  // (8,16,28,28)
    const float* W1   = (const float*)d_in[1];  // (4,64)
    const float* b1   = (const float*)d_in[2];  // (64,)
    const float* W2   = (const float*)d_in[3];  // (64,256)
    const float* b2   = (const float*)d_in[4];  // (256,)
    const float* bias = (const float*)d_in[5];  // (16,1,1)
    float* out = (float*)d_out;                 // (8,16,28,28) fp32

    char* ws = (char*)d_ws;
    short* vTb  = (short*)(ws);                 // 28*128*32*2 = 229376 B
    short* W2b  = (short*)(ws + 229376);        // 16384*2     =  32768 B
    float* Vsum = (float*)(ws + 262144);        // 28*128*4    =  14336 B

    prep_kernel<<<NI + 1, 256, 0, stream>>>(v, W2, vTb, W2b, Vsum);
    fused_kernel<<<PQ, 256, 0, stream>>>(vTb, W2b, Vsum, W1, b1, b2, bias, out);
}